// Round 6
// baseline (356.742 us; speedup 1.0000x reference)
//
#include <hip/hip_runtime.h>

#define IN_C 256
#define H1 8
#define C1 32
#define F1 256   // H1*C1
#define OC 16
#define NEG 0.2f

typedef short short8 __attribute__((ext_vector_type(8)));
typedef unsigned short ushort8 __attribute__((ext_vector_type(8)));
typedef float floatx4 __attribute__((ext_vector_type(4)));

__device__ __forceinline__ unsigned short f2bf(float f) {
    unsigned u = __builtin_bit_cast(unsigned, f);
    u = (u + 0x7fffu + ((u >> 16) & 1u)) >> 16;
    return (unsigned short)u;
}
__device__ __forceinline__ float bf2f(unsigned short h) {
    unsigned u = ((unsigned)h) << 16;
    return __builtin_bit_cast(float, u);
}

// ---------------- convert x -> bf16 ----------------
__global__ __launch_bounds__(256) void k_cvt_x(const float* __restrict__ x,
                                               unsigned short* __restrict__ xb, int n4)
{
    int idx = blockIdx.x * 256 + threadIdx.x;
    if (idx >= n4) return;
    float4 v = ((const float4*)x)[idx];
    ushort4 o;
    o.x = f2bf(v.x); o.y = f2bf(v.y); o.z = f2bf(v.z); o.w = f2bf(v.w);
    ((ushort4*)xb)[idx] = o;
}

// ---------------- W1,W2 -> bf16 transposed ----------------
__global__ __launch_bounds__(256) void k_wcvt(const float* __restrict__ W1,
                                              const float* __restrict__ W2,
                                              unsigned short* __restrict__ w1t,
                                              unsigned short* __restrict__ w2t)
{
    int idx = blockIdx.x * 256 + threadIdx.x;   // 65536 + 4096
    if (idx < 65536) {
        int n = idx >> 8, k = idx & 255;
        w1t[n * 256 + k] = f2bf(W1[k * 256 + n]);
    } else if (idx < 65536 + 4096) {
        int r = idx - 65536;
        int n = r >> 8, k = r & 255;        // n<16, k<256
        w2t[n * 256 + k] = f2bf(W2[k * 16 + n]);
    }
}

// ---------------- L1 GEMM (bf16 MFMA): xl1b[M,256] = xb[M,256] @ W1 ----------------
__global__ __launch_bounds__(256) void k_gemm1(const unsigned short* __restrict__ A,
                                               const unsigned short* __restrict__ Bt,
                                               unsigned short* __restrict__ Cb, int M)
{
    __shared__ short As[128][40];   // +8 pad: conflict-free ds_read_b128
    __shared__ short Bs[128][40];
    const int tid  = threadIdx.x;
    const int lane = tid & 63;
    const int w    = tid >> 6;
    const int bm   = blockIdx.x * 128;
    const int bn   = blockIdx.y * 128;
    const int wm   = (w >> 1) * 64;
    const int wn   = (w & 1) * 64;
    const int srow = tid >> 1;          // staging row
    const int soff = (tid & 1) * 16;    // 16 shorts = 32B
    floatx4 acc[4][4] = {};
    for (int k0 = 0; k0 < 256; k0 += 32) {
        __syncthreads();
        {
            int gr = bm + srow;
            ushort8 v0 = {0,0,0,0,0,0,0,0}, v1 = {0,0,0,0,0,0,0,0};
            if (gr < M) {
                const ushort8* p = (const ushort8*)(A + (size_t)gr * 256 + k0 + soff);
                v0 = p[0]; v1 = p[1];
            }
            *(ushort8*)&As[srow][soff]     = v0;
            *(ushort8*)&As[srow][soff + 8] = v1;
        }
        {
            const ushort8* p = (const ushort8*)(Bt + (size_t)(bn + srow) * 256 + k0 + soff);
            *(ushort8*)&Bs[srow][soff]     = p[0];
            *(ushort8*)&Bs[srow][soff + 8] = p[1];
        }
        __syncthreads();
        short8 af[4], bf[4];
        const int q8 = (lane >> 4) * 8;
        const int l15 = lane & 15;
#pragma unroll
        for (int i = 0; i < 4; ++i) af[i] = *(const short8*)&As[wm + i * 16 + l15][q8];
#pragma unroll
        for (int j = 0; j < 4; ++j) bf[j] = *(const short8*)&Bs[wn + j * 16 + l15][q8];
#pragma unroll
        for (int i = 0; i < 4; ++i)
#pragma unroll
            for (int j = 0; j < 4; ++j)
                acc[i][j] = __builtin_amdgcn_mfma_f32_16x16x32_bf16(af[i], bf[j], acc[i][j], 0, 0, 0);
    }
    const int l15 = lane & 15;
    const int rq  = (lane >> 4) * 4;
#pragma unroll
    for (int i = 0; i < 4; ++i) {
#pragma unroll
        for (int reg = 0; reg < 4; ++reg) {
            int gr = bm + wm + i * 16 + rq + reg;
            if (gr < M) {
#pragma unroll
                for (int j = 0; j < 4; ++j)
                    Cb[(size_t)gr * 256 + bn + wn + j * 16 + l15] = f2bf(acc[i][j][reg]);
            }
        }
    }
}

// ---------------- L1 attention coefficients from bf16 xl ----------------
__global__ __launch_bounds__(256) void k_att1(const unsigned short* __restrict__ xl,
                                              const float* __restrict__ att_s,
                                              const float* __restrict__ att_d,
                                              float* __restrict__ asrc,
                                              float* __restrict__ adst, int N)
{
    int idx = blockIdx.x * 256 + threadIdx.x;
    if (idx >= N * H1) return;
    int i = idx >> 3, h = idx & 7;
    const ushort4* xr = (const ushort4*)(xl + (size_t)i * F1 + h * C1);
    const float* s = att_s + h * C1;
    const float* d = att_d + h * C1;
    float s1 = 0.f, s2 = 0.f;
#pragma unroll
    for (int c4 = 0; c4 < 8; ++c4) {
        ushort4 v = xr[c4];
        float f0 = bf2f(v.x), f1 = bf2f(v.y), f2 = bf2f(v.z), f3 = bf2f(v.w);
        int c = c4 * 4;
        s1 += f0 * s[c] + f1 * s[c+1] + f2 * s[c+2] + f3 * s[c+3];
        s2 += f0 * d[c] + f1 * d[c+1] + f2 * d[c+2] + f3 * d[c+3];
    }
    asrc[idx] = s1; adst[idx] = s2;
}

// ---------------- CSR build ----------------
__global__ __launch_bounds__(256) void k_hist(const int* __restrict__ ei,
                                              int* __restrict__ cnt, int E)
{
    int e = blockIdx.x * 256 + threadIdx.x;
    if (e < E) atomicAdd(&cnt[ei[E + e]], 1);
}

__global__ __launch_bounds__(256) void k_scan_a(const int* __restrict__ cnt,
                                                int* __restrict__ rp,
                                                int* __restrict__ bsum, int N)
{
    __shared__ int ws4[4];
    int t = threadIdx.x, lane = t & 63, wid = t >> 6;
    int i = blockIdx.x * 256 + t;
    int v = (i < N) ? cnt[i] : 0;
    int incl = v;
#pragma unroll
    for (int off = 1; off < 64; off <<= 1) {
        int tv = __shfl_up(incl, off, 64);
        if (lane >= off) incl += tv;
    }
    if (lane == 63) ws4[wid] = incl;
    __syncthreads();
    int add = 0;
    for (int w = 0; w < wid; ++w) add += ws4[w];
    incl += add;
    if (i < N) rp[i + 1] = incl;
    if (t == 255) bsum[blockIdx.x] = incl;
}

__global__ __launch_bounds__(256) void k_scan_b(const int* __restrict__ bsum,
                                                int* __restrict__ boff, int NB)
{
    __shared__ int ws4[4];
    int t = threadIdx.x, lane = t & 63, wid = t >> 6;
    int i0 = t * 4;
    int v[4];
#pragma unroll
    for (int k = 0; k < 4; ++k) { int i = i0 + k; v[k] = (i < NB) ? bsum[i] : 0; }
    int s = v[0] + v[1] + v[2] + v[3];
    int incl = s;
#pragma unroll
    for (int off = 1; off < 64; off <<= 1) {
        int tv = __shfl_up(incl, off, 64);
        if (lane >= off) incl += tv;
    }
    if (lane == 63) ws4[wid] = incl;
    __syncthreads();
    int wpre = 0;
    for (int w = 0; w < wid; ++w) wpre += ws4[w];
    int run = wpre + incl - s;
#pragma unroll
    for (int k = 0; k < 4; ++k) {
        int i = i0 + k;
        if (i < NB) boff[i] = run;
        run += v[k];
    }
}

__global__ __launch_bounds__(256) void k_scan_c(int* __restrict__ rp,
                                                const int* __restrict__ boff, int N)
{
    int i = blockIdx.x * 256 + threadIdx.x;
    if (i < N) rp[i + 1] += boff[blockIdx.x];
    if (i == 0) rp[0] = 0;
}

__global__ __launch_bounds__(256) void k_scatter(const int* __restrict__ ei,
                                                 int* __restrict__ cur,
                                                 int* __restrict__ ssrc, int E)
{
    int e = blockIdx.x * 256 + threadIdx.x;
    if (e >= E) return;
    int s = ei[e];
    int d = ei[E + e];
    int pos = atomicAdd(&cur[d], 1);
    ssrc[pos] = s;
}

// ---------------- L1 gather: 2 waves per node (split CSR range), LDS combine ----------------
__global__ __launch_bounds__(256) void k_gather1(const int* __restrict__ rp,
                                                 const int* __restrict__ ssrc,
                                                 const unsigned short* __restrict__ xl,
                                                 const float* __restrict__ asrc,
                                                 const float* __restrict__ adst,
                                                 const float* __restrict__ bias,
                                                 unsigned short* __restrict__ hout, int N)
{
    __shared__ float accs[2][256];
    __shared__ float dens[2][8];
    int tid  = threadIdx.x;
    int lane = tid & 63;
    int pair = tid >> 7;            // node slot within block (0/1)
    int half = (tid >> 6) & 1;      // which wave of the pair
    int node = blockIdx.x * 2 + pair;
    bool valid = node < N;
    int h  = lane >> 3;
    int cb = lane * 4;
    float ax = 0.f, ay = 0.f, az = 0.f, aw = 0.f, den = 0.f;
    float ad = 0.f;
    if (valid) {
        ad = adst[(size_t)node * H1 + h];
        int jb0 = rp[node], je0 = rp[node + 1];
        int mid = (jb0 + je0) >> 1;
        int jb = half ? mid : jb0;
        int je = half ? je0 : mid;
        if (half == 0) {
            // self-loop
            float e = asrc[(size_t)node * H1 + h] + ad;
            e = e >= 0.f ? e : NEG * e;
            float w = __expf(e);
            ushort4 xv = *(const ushort4*)(xl + (size_t)node * F1 + cb);
            ax = w * bf2f(xv.x); ay = w * bf2f(xv.y);
            az = w * bf2f(xv.z); aw = w * bf2f(xv.w);
            den = w;
        }
        int j = jb;
        for (; j + 4 <= je; j += 4) {
            int s0 = ssrc[j], s1 = ssrc[j+1], s2 = ssrc[j+2], s3 = ssrc[j+3];
            float e0 = asrc[(size_t)s0 * H1 + h] + ad;
            float e1 = asrc[(size_t)s1 * H1 + h] + ad;
            float e2 = asrc[(size_t)s2 * H1 + h] + ad;
            float e3 = asrc[(size_t)s3 * H1 + h] + ad;
            ushort4 r0 = *(const ushort4*)(xl + (size_t)s0 * F1 + cb);
            ushort4 r1 = *(const ushort4*)(xl + (size_t)s1 * F1 + cb);
            ushort4 r2 = *(const ushort4*)(xl + (size_t)s2 * F1 + cb);
            ushort4 r3 = *(const ushort4*)(xl + (size_t)s3 * F1 + cb);
            e0 = e0 >= 0.f ? e0 : NEG * e0;  float w0 = __expf(e0);
            e1 = e1 >= 0.f ? e1 : NEG * e1;  float w1 = __expf(e1);
            e2 = e2 >= 0.f ? e2 : NEG * e2;  float w2 = __expf(e2);
            e3 = e3 >= 0.f ? e3 : NEG * e3;  float w3 = __expf(e3);
            den += w0 + w1 + w2 + w3;
            ax += w0*bf2f(r0.x) + w1*bf2f(r1.x) + w2*bf2f(r2.x) + w3*bf2f(r3.x);
            ay += w0*bf2f(r0.y) + w1*bf2f(r1.y) + w2*bf2f(r2.y) + w3*bf2f(r3.y);
            az += w0*bf2f(r0.z) + w1*bf2f(r1.z) + w2*bf2f(r2.z) + w3*bf2f(r3.z);
            aw += w0*bf2f(r0.w) + w1*bf2f(r1.w) + w2*bf2f(r2.w) + w3*bf2f(r3.w);
        }
        for (; j < je; ++j) {
            int s = ssrc[j];
            float ev = asrc[(size_t)s * H1 + h] + ad;
            ev = ev >= 0.f ? ev : NEG * ev;
            float wv = __expf(ev);
            ushort4 sv = *(const ushort4*)(xl + (size_t)s * F1 + cb);
            ax += wv * bf2f(sv.x); ay += wv * bf2f(sv.y);
            az += wv * bf2f(sv.z); aw += wv * bf2f(sv.w);
            den += wv;
        }
    }
    if (half == 1) {
        accs[pair][cb+0] = ax; accs[pair][cb+1] = ay;
        accs[pair][cb+2] = az; accs[pair][cb+3] = aw;
        if ((lane & 7) == 0) dens[pair][h] = den;
    }
    __syncthreads();
    if (half == 0 && valid) {
        ax += accs[pair][cb+0]; ay += accs[pair][cb+1];
        az += accs[pair][cb+2]; aw += accs[pair][cb+3];
        den += dens[pair][h];
        float inv = 1.f / (den + 1e-16f);
        float4 bv = *(const float4*)(bias + cb);
        ushort4 o;
        o.x = f2bf(fmaxf(ax * inv + bv.x, 0.f));
        o.y = f2bf(fmaxf(ay * inv + bv.y, 0.f));
        o.z = f2bf(fmaxf(az * inv + bv.z, 0.f));
        o.w = f2bf(fmaxf(aw * inv + bv.w, 0.f));
        *(ushort4*)(hout + (size_t)node * F1 + cb) = o;
    }
}

// ---------------- L2 GEMM (bf16 MFMA, no LDS) + fused att2 epilogue ----------------
__global__ __launch_bounds__(256) void k_gemm2(const unsigned short* __restrict__ Hm,
                                               const unsigned short* __restrict__ W2t,
                                               const float* __restrict__ as2,
                                               const float* __restrict__ ad2,
                                               unsigned short* __restrict__ xl2b,
                                               float* __restrict__ asrc,
                                               float* __restrict__ adst, int N)
{
    const int lane = threadIdx.x & 63;
    const int wid  = threadIdx.x >> 6;
    const int rowbase = blockIdx.x * 64 + wid * 16;
    const int col = lane & 15;
    const int q8  = (lane >> 4) * 8;
    const int m   = rowbase + col;            // A-frag row
    const bool mv = m < N;
    const unsigned short* arow = Hm + (size_t)m * 256 + q8;
    const unsigned short* brow = W2t + (size_t)col * 256 + q8;
    floatx4 acc = {0.f, 0.f, 0.f, 0.f};
#pragma unroll
    for (int t = 0; t < 8; ++t) {
        short8 af = {0,0,0,0,0,0,0,0};
        if (mv) af = *(const short8*)(arow + t * 32);
        short8 bf = *(const short8*)(brow + t * 32);
        acc = __builtin_amdgcn_mfma_f32_16x16x32_bf16(af, bf, acc, 0, 0, 0);
    }
    float s_as = as2[col], s_ad = ad2[col];
    const int rq = (lane >> 4) * 4;
#pragma unroll
    for (int reg = 0; reg < 4; ++reg) {
        int row = rowbase + rq + reg;
        float v = acc[reg];
        float s1 = v * s_as, s2 = v * s_ad;
#pragma unroll
        for (int o = 1; o < 16; o <<= 1) { s1 += __shfl_xor(s1, o, 16); s2 += __shfl_xor(s2, o, 16); }
        if (row < N) {
            xl2b[(size_t)row * OC + col] = f2bf(v);
            if (col == 0) { asrc[row] = s1; adst[row] = s2; }
        }
    }
}

// ---------------- L2 gather: full wave per node, 4 edge-slots x 16 channels ----------------
__global__ __launch_bounds__(256) void k_gather2(const int* __restrict__ rp,
                                                 const int* __restrict__ ssrc,
                                                 const unsigned short* __restrict__ xl2b,
                                                 const float* __restrict__ asrc,
                                                 const float* __restrict__ adst,
                                                 const float* __restrict__ bias,
                                                 float* __restrict__ out, int N)
{
    int lane = threadIdx.x & 63;
    int slot = lane >> 4;          // 0..3 edge slot
    int sub  = lane & 15;          // channel
    int node = blockIdx.x * 4 + (threadIdx.x >> 6);
    if (node >= N) return;
    float ad = adst[node];
    float acc = 0.f, den = 0.f;
    if (slot == 0) {
        float e = asrc[node] + ad;
        e = e >= 0.f ? e : NEG * e;
        float w = __expf(e);
        acc = w * bf2f(xl2b[(size_t)node * OC + sub]);
        den = w;
    }
    int jb = rp[node], je = rp[node + 1];
    for (int j = jb + slot; j < je; j += 4) {
        int s = ssrc[j];
        float ev = asrc[s] + ad;
        ev = ev >= 0.f ? ev : NEG * ev;
        float wv = __expf(ev);
        acc += wv * bf2f(xl2b[(size_t)s * OC + sub]);
        den += wv;
    }
    // reduce across the 4 slots (lanes sub, sub+16, sub+32, sub+48)
    acc += __shfl_xor(acc, 16, 64);  den += __shfl_xor(den, 16, 64);
    acc += __shfl_xor(acc, 32, 64);  den += __shfl_xor(den, 32, 64);
    if (slot == 0) {
        float v = acc / (den + 1e-16f) + bias[sub];
        float m = v;
#pragma unroll
        for (int o = 1; o < 16; o <<= 1) m = fmaxf(m, __shfl_xor(m, o, 16));
        float ex = __expf(v - m);
        float ss = ex;
#pragma unroll
        for (int o = 1; o < 16; o <<= 1) ss += __shfl_xor(ss, o, 16);
        out[(size_t)node * OC + sub] = v - m - logf(ss);
    }
}

extern "C" void kernel_launch(void* const* d_in, const int* in_sizes, int n_in,
                              void* d_out, int out_size, void* d_ws, size_t ws_size,
                              hipStream_t stream)
{
    const float* x   = (const float*)d_in[0];
    const int*   ei  = (const int*)d_in[1];
    const float* W1  = (const float*)d_in[2];
    const float* as1 = (const float*)d_in[3];
    const float* ad1 = (const float*)d_in[4];
    const float* b1  = (const float*)d_in[5];
    const float* W2  = (const float*)d_in[6];
    const float* as2 = (const float*)d_in[7];
    const float* ad2 = (const float*)d_in[8];
    const float* b2  = (const float*)d_in[9];
    float* out = (float*)d_out;

    const int N = in_sizes[0] / IN_C;   // 50000
    const int E = in_sizes[1] / 2;      // 800000
    const int NB = (N + 255) / 256;     // 196 scan blocks

    char* base = (char*)d_ws;
    unsigned short* xb   = (unsigned short*)base;                      // N*256 bf16
    unsigned short* xl1b = xb + (size_t)N * F1;                        // N*256 bf16
    unsigned short* hb   = xl1b + (size_t)N * F1;                      // N*256 bf16
    unsigned short* w1t  = hb + (size_t)N * F1;                        // 256*256 bf16
    unsigned short* w2t  = w1t + 256 * 256;                            // 16*256 bf16
    unsigned short* xl2b = w2t + 16 * 256;                             // N*16 bf16
    float* asrc1 = (float*)(xl2b + (size_t)N * OC);                    // N*H1
    float* adst1 = asrc1 + (size_t)N * H1;                             // N*H1
    float* asrc2 = adst1 + (size_t)N * H1;                             // N
    float* adst2 = asrc2 + N;                                          // N
    int*   rp    = (int*)(adst2 + N);                                  // N+1
    int*   cnt   = rp + (N + 1);                                       // N
    int*   cur   = cnt + N;                                            // N
    int*   bsum  = cur + N;                                            // 1024
    int*   boff  = bsum + 1024;                                        // 1024
    int*   ssrc  = boff + 1024;                                        // E

    // ---- CSR build ----
    hipMemsetAsync(cnt, 0, (size_t)N * sizeof(int), stream);
    k_hist<<<(E + 255) / 256, 256, 0, stream>>>(ei, cnt, E);
    k_scan_a<<<NB, 256, 0, stream>>>(cnt, rp, bsum, N);
    k_scan_b<<<1, 256, 0, stream>>>(bsum, boff, NB);
    k_scan_c<<<NB, 256, 0, stream>>>(rp, boff, N);
    hipMemcpyAsync(cur, rp, (size_t)N * sizeof(int), hipMemcpyDeviceToDevice, stream);
    k_scatter<<<(E + 255) / 256, 256, 0, stream>>>(ei, cur, ssrc, E);

    // ---- conversions ----
    k_cvt_x<<<(N * 64 + 255) / 256, 256, 0, stream>>>(x, xb, N * 64);
    k_wcvt<<<(65536 + 4096) / 256, 256, 0, stream>>>(W1, W2, w1t, w2t);

    // ---- layer 1 ----
    k_gemm1<<<dim3((N + 127) / 128, 2), 256, 0, stream>>>(xb, w1t, xl1b, N);
    k_att1<<<(N * H1 + 255) / 256, 256, 0, stream>>>(xl1b, as1, ad1, asrc1, adst1, N);
    k_gather1<<<(N + 1) / 2, 256, 0, stream>>>(rp, ssrc, xl1b, asrc1, adst1, b1, hb, N);

    // ---- layer 2 ----
    k_gemm2<<<(N + 63) / 64, 256, 0, stream>>>(hb, w2t, as2, ad2, xl2b, asrc2, adst2, N);
    k_gather2<<<(N + 3) / 4, 256, 0, stream>>>(rp, ssrc, xl2b, asrc2, adst2, b2, out, N);
}

// Round 7
// 333.542 us; speedup vs baseline: 1.0696x; 1.0696x over previous
//
#include <hip/hip_runtime.h>

#define IN_C 256
#define H1 8
#define C1 32
#define F1 256   // H1*C1
#define OC 16
#define NEG 0.2f

typedef short short8 __attribute__((ext_vector_type(8)));
typedef unsigned short ushort8 __attribute__((ext_vector_type(8)));
typedef float floatx4 __attribute__((ext_vector_type(4)));

__device__ __forceinline__ unsigned short f2bf(float f) {
    unsigned u = __builtin_bit_cast(unsigned, f);
    u = (u + 0x7fffu + ((u >> 16) & 1u)) >> 16;
    return (unsigned short)u;
}
__device__ __forceinline__ float bf2f(unsigned short h) {
    unsigned u = ((unsigned)h) << 16;
    return __builtin_bit_cast(float, u);
}

// ---------------- fused: hist (dst histogram) + W1/W2 bf16-transpose ----------------
__global__ __launch_bounds__(256) void k_fuse0(const int* __restrict__ ei,
                                               int* __restrict__ cnt,
                                               const float* __restrict__ W1,
                                               const float* __restrict__ W2,
                                               unsigned short* __restrict__ w1t,
                                               unsigned short* __restrict__ w2t, int E)
{
    int gid = blockIdx.x * 256 + threadIdx.x;
    if (gid < E) atomicAdd(&cnt[ei[E + gid]], 1);
    if (gid < 65536) {
        int n = gid >> 8, k = gid & 255;
        w1t[n * 256 + k] = f2bf(W1[k * 256 + n]);
    } else if (gid < 65536 + 4096) {
        int r = gid - 65536;
        int n = r >> 8, k = r & 255;        // n<16, k<256
        w2t[n * 256 + k] = f2bf(W2[k * 16 + n]);
    }
}

// ---------------- L1 GEMM (bf16 MFMA, fp32 A staged+converted): xl1b = x @ W1 ----------------
__global__ __launch_bounds__(256) void k_gemm1(const float* __restrict__ A,
                                               const unsigned short* __restrict__ Bt,
                                               unsigned short* __restrict__ Cb, int M)
{
    __shared__ short As[128][40];   // +8 pad: conflict-free ds_read_b128
    __shared__ short Bs[128][40];
    const int tid  = threadIdx.x;
    const int lane = tid & 63;
    const int w    = tid >> 6;
    const int bm   = blockIdx.x * 128;
    const int bn   = blockIdx.y * 128;
    const int wm   = (w >> 1) * 64;
    const int wn   = (w & 1) * 64;
    const int srow = tid >> 1;          // staging row
    const int soff = (tid & 1) * 16;    // 16 elems
    floatx4 acc[4][4] = {};
    for (int k0 = 0; k0 < 256; k0 += 32) {
        __syncthreads();
        {   // stage A 128x32: fp32 load -> bf16 LDS
            int gr = bm + srow;
            float4 f0 = {0,0,0,0}, f1 = {0,0,0,0}, f2 = {0,0,0,0}, f3 = {0,0,0,0};
            if (gr < M) {
                const float4* p = (const float4*)(A + (size_t)gr * 256 + k0 + soff);
                f0 = p[0]; f1 = p[1]; f2 = p[2]; f3 = p[3];
            }
            ushort8 v0, v1;
            v0[0]=f2bf(f0.x); v0[1]=f2bf(f0.y); v0[2]=f2bf(f0.z); v0[3]=f2bf(f0.w);
            v0[4]=f2bf(f1.x); v0[5]=f2bf(f1.y); v0[6]=f2bf(f1.z); v0[7]=f2bf(f1.w);
            v1[0]=f2bf(f2.x); v1[1]=f2bf(f2.y); v1[2]=f2bf(f2.z); v1[3]=f2bf(f2.w);
            v1[4]=f2bf(f3.x); v1[5]=f2bf(f3.y); v1[6]=f2bf(f3.z); v1[7]=f2bf(f3.w);
            *(ushort8*)&As[srow][soff]     = v0;
            *(ushort8*)&As[srow][soff + 8] = v1;
        }
        {   // stage B 128x32 from w1t rows (already bf16)
            const ushort8* p = (const ushort8*)(Bt + (size_t)(bn + srow) * 256 + k0 + soff);
            *(ushort8*)&Bs[srow][soff]     = p[0];
            *(ushort8*)&Bs[srow][soff + 8] = p[1];
        }
        __syncthreads();
        short8 af[4], bf[4];
        const int q8 = (lane >> 4) * 8;
        const int l15 = lane & 15;
#pragma unroll
        for (int i = 0; i < 4; ++i) af[i] = *(const short8*)&As[wm + i * 16 + l15][q8];
#pragma unroll
        for (int j = 0; j < 4; ++j) bf[j] = *(const short8*)&Bs[wn + j * 16 + l15][q8];
#pragma unroll
        for (int i = 0; i < 4; ++i)
#pragma unroll
            for (int j = 0; j < 4; ++j)
                acc[i][j] = __builtin_amdgcn_mfma_f32_16x16x32_bf16(af[i], bf[j], acc[i][j], 0, 0, 0);
    }
    const int l15 = lane & 15;
    const int rq  = (lane >> 4) * 4;
#pragma unroll
    for (int i = 0; i < 4; ++i) {
#pragma unroll
        for (int reg = 0; reg < 4; ++reg) {
            int gr = bm + wm + i * 16 + rq + reg;
            if (gr < M) {
#pragma unroll
                for (int j = 0; j < 4; ++j)
                    Cb[(size_t)gr * 256 + bn + wn + j * 16 + l15] = f2bf(acc[i][j][reg]);
            }
        }
    }
}

// ---------------- L1 attention coefficients from bf16 xl ----------------
__global__ __launch_bounds__(256) void k_att1(const unsigned short* __restrict__ xl,
                                              const float* __restrict__ att_s,
                                              const float* __restrict__ att_d,
                                              float* __restrict__ asrc,
                                              float* __restrict__ adst, int N)
{
    int idx = blockIdx.x * 256 + threadIdx.x;
    if (idx >= N * H1) return;
    int i = idx >> 3, h = idx & 7;
    const ushort4* xr = (const ushort4*)(xl + (size_t)i * F1 + h * C1);
    const float* s = att_s + h * C1;
    const float* d = att_d + h * C1;
    float s1 = 0.f, s2 = 0.f;
#pragma unroll
    for (int c4 = 0; c4 < 8; ++c4) {
        ushort4 v = xr[c4];
        float f0 = bf2f(v.x), f1 = bf2f(v.y), f2 = bf2f(v.z), f3 = bf2f(v.w);
        int c = c4 * 4;
        s1 += f0 * s[c] + f1 * s[c+1] + f2 * s[c+2] + f3 * s[c+3];
        s2 += f0 * d[c] + f1 * d[c+1] + f2 * d[c+2] + f3 * d[c+3];
    }
    asrc[idx] = s1; adst[idx] = s2;
}

// ---------------- CSR scan ----------------
__global__ __launch_bounds__(256) void k_scan_a(const int* __restrict__ cnt,
                                                int* __restrict__ rp,
                                                int* __restrict__ bsum, int N)
{
    __shared__ int ws4[4];
    int t = threadIdx.x, lane = t & 63, wid = t >> 6;
    int i = blockIdx.x * 256 + t;
    int v = (i < N) ? cnt[i] : 0;
    int incl = v;
#pragma unroll
    for (int off = 1; off < 64; off <<= 1) {
        int tv = __shfl_up(incl, off, 64);
        if (lane >= off) incl += tv;
    }
    if (lane == 63) ws4[wid] = incl;
    __syncthreads();
    int add = 0;
    for (int w = 0; w < wid; ++w) add += ws4[w];
    incl += add;
    if (i < N) rp[i + 1] = incl;
    if (t == 255) bsum[blockIdx.x] = incl;
}

__global__ __launch_bounds__(256) void k_scan_b(const int* __restrict__ bsum,
                                                int* __restrict__ boff, int NB)
{
    __shared__ int ws4[4];
    int t = threadIdx.x, lane = t & 63, wid = t >> 6;
    int i0 = t * 4;
    int v[4];
#pragma unroll
    for (int k = 0; k < 4; ++k) { int i = i0 + k; v[k] = (i < NB) ? bsum[i] : 0; }
    int s = v[0] + v[1] + v[2] + v[3];
    int incl = s;
#pragma unroll
    for (int off = 1; off < 64; off <<= 1) {
        int tv = __shfl_up(incl, off, 64);
        if (lane >= off) incl += tv;
    }
    if (lane == 63) ws4[wid] = incl;
    __syncthreads();
    int wpre = 0;
    for (int w = 0; w < wid; ++w) wpre += ws4[w];
    int run = wpre + incl - s;
#pragma unroll
    for (int k = 0; k < 4; ++k) {
        int i = i0 + k;
        if (i < NB) boff[i] = run;
        run += v[k];
    }
}

// phase C: add block offsets; also produce cur = exclusive prefix (rp[i])
__global__ __launch_bounds__(256) void k_scan_c(int* __restrict__ rp,
                                                const int* __restrict__ boff,
                                                const int* __restrict__ cnt,
                                                int* __restrict__ cur, int N)
{
    int i = blockIdx.x * 256 + threadIdx.x;
    if (i < N) {
        int v = rp[i + 1] + boff[blockIdx.x];
        rp[i + 1] = v;
        cur[i] = v - cnt[i];
    }
    if (i == 0) rp[0] = 0;
}

__global__ __launch_bounds__(256) void k_scatter(const int* __restrict__ ei,
                                                 int* __restrict__ cur,
                                                 int* __restrict__ ssrc, int E)
{
    int e = blockIdx.x * 256 + threadIdx.x;
    if (e >= E) return;
    int s = ei[e];
    int d = ei[E + e];
    int pos = atomicAdd(&cur[d], 1);
    ssrc[pos] = s;
}

// ---------------- L1 gather (bf16 rows, 4x unrolled) — R5 proven version ----------------
__global__ __launch_bounds__(256) void k_gather1(const int* __restrict__ rp,
                                                 const int* __restrict__ ssrc,
                                                 const unsigned short* __restrict__ xl,
                                                 const float* __restrict__ asrc,
                                                 const float* __restrict__ adst,
                                                 const float* __restrict__ bias,
                                                 unsigned short* __restrict__ hout, int N)
{
    int lane = threadIdx.x & 63;
    int node = blockIdx.x * 4 + (threadIdx.x >> 6);
    if (node >= N) return;
    int h  = lane >> 3;
    int cb = lane * 4;
    float ad = adst[(size_t)node * H1 + h];
    float e = asrc[(size_t)node * H1 + h] + ad;
    e = e >= 0.f ? e : NEG * e;
    float w = __expf(e);
    ushort4 xv = *(const ushort4*)(xl + (size_t)node * F1 + cb);
    float ax = w * bf2f(xv.x), ay = w * bf2f(xv.y), az = w * bf2f(xv.z), aw = w * bf2f(xv.w);
    float den = w;
    int jb = rp[node], je = rp[node + 1];
    int j = jb;
    for (; j + 4 <= je; j += 4) {
        int s0 = ssrc[j], s1 = ssrc[j+1], s2 = ssrc[j+2], s3 = ssrc[j+3];
        float e0 = asrc[(size_t)s0 * H1 + h] + ad;
        float e1 = asrc[(size_t)s1 * H1 + h] + ad;
        float e2 = asrc[(size_t)s2 * H1 + h] + ad;
        float e3 = asrc[(size_t)s3 * H1 + h] + ad;
        ushort4 r0 = *(const ushort4*)(xl + (size_t)s0 * F1 + cb);
        ushort4 r1 = *(const ushort4*)(xl + (size_t)s1 * F1 + cb);
        ushort4 r2 = *(const ushort4*)(xl + (size_t)s2 * F1 + cb);
        ushort4 r3 = *(const ushort4*)(xl + (size_t)s3 * F1 + cb);
        e0 = e0 >= 0.f ? e0 : NEG * e0;  float w0 = __expf(e0);
        e1 = e1 >= 0.f ? e1 : NEG * e1;  float w1 = __expf(e1);
        e2 = e2 >= 0.f ? e2 : NEG * e2;  float w2 = __expf(e2);
        e3 = e3 >= 0.f ? e3 : NEG * e3;  float w3 = __expf(e3);
        den += w0 + w1 + w2 + w3;
        ax += w0*bf2f(r0.x) + w1*bf2f(r1.x) + w2*bf2f(r2.x) + w3*bf2f(r3.x);
        ay += w0*bf2f(r0.y) + w1*bf2f(r1.y) + w2*bf2f(r2.y) + w3*bf2f(r3.y);
        az += w0*bf2f(r0.z) + w1*bf2f(r1.z) + w2*bf2f(r2.z) + w3*bf2f(r3.z);
        aw += w0*bf2f(r0.w) + w1*bf2f(r1.w) + w2*bf2f(r2.w) + w3*bf2f(r3.w);
    }
    for (; j < je; ++j) {
        int s = ssrc[j];
        float ev = asrc[(size_t)s * H1 + h] + ad;
        ev = ev >= 0.f ? ev : NEG * ev;
        float wv = __expf(ev);
        ushort4 sv = *(const ushort4*)(xl + (size_t)s * F1 + cb);
        ax += wv * bf2f(sv.x); ay += wv * bf2f(sv.y);
        az += wv * bf2f(sv.z); aw += wv * bf2f(sv.w);
        den += wv;
    }
    float inv = 1.f / (den + 1e-16f);
    float4 bv = *(const float4*)(bias + cb);
    ushort4 o;
    o.x = f2bf(fmaxf(ax * inv + bv.x, 0.f));
    o.y = f2bf(fmaxf(ay * inv + bv.y, 0.f));
    o.z = f2bf(fmaxf(az * inv + bv.z, 0.f));
    o.w = f2bf(fmaxf(aw * inv + bv.w, 0.f));
    *(ushort4*)(hout + (size_t)node * F1 + cb) = o;
}

// ---------------- L2 GEMM (bf16 MFMA, no LDS) + fused att2 epilogue ----------------
__global__ __launch_bounds__(256) void k_gemm2(const unsigned short* __restrict__ Hm,
                                               const unsigned short* __restrict__ W2t,
                                               const float* __restrict__ as2,
                                               const float* __restrict__ ad2,
                                               unsigned short* __restrict__ xl2b,
                                               float* __restrict__ asrc,
                                               float* __restrict__ adst, int N)
{
    const int lane = threadIdx.x & 63;
    const int wid  = threadIdx.x >> 6;
    const int rowbase = blockIdx.x * 64 + wid * 16;
    const int col = lane & 15;
    const int q8  = (lane >> 4) * 8;
    const int m   = rowbase + col;            // A-frag row
    const bool mv = m < N;
    const unsigned short* arow = Hm + (size_t)m * 256 + q8;
    const unsigned short* brow = W2t + (size_t)col * 256 + q8;
    floatx4 acc = {0.f, 0.f, 0.f, 0.f};
#pragma unroll
    for (int t = 0; t < 8; ++t) {
        short8 af = {0,0,0,0,0,0,0,0};
        if (mv) af = *(const short8*)(arow + t * 32);
        short8 bf = *(const short8*)(brow + t * 32);
        acc = __builtin_amdgcn_mfma_f32_16x16x32_bf16(af, bf, acc, 0, 0, 0);
    }
    float s_as = as2[col], s_ad = ad2[col];
    const int rq = (lane >> 4) * 4;
#pragma unroll
    for (int reg = 0; reg < 4; ++reg) {
        int row = rowbase + rq + reg;
        float v = acc[reg];
        float s1 = v * s_as, s2 = v * s_ad;
#pragma unroll
        for (int o = 1; o < 16; o <<= 1) { s1 += __shfl_xor(s1, o, 16); s2 += __shfl_xor(s2, o, 16); }
        if (row < N) {
            xl2b[(size_t)row * OC + col] = f2bf(v);
            if (col == 0) { asrc[row] = s1; adst[row] = s2; }
        }
    }
}

// ---------------- L2 gather (bf16 rows, 4x unrolled) + log_softmax — R5 proven version ----------------
__global__ __launch_bounds__(256) void k_gather2(const int* __restrict__ rp,
                                                 const int* __restrict__ ssrc,
                                                 const unsigned short* __restrict__ xl2b,
                                                 const float* __restrict__ asrc,
                                                 const float* __restrict__ adst,
                                                 const float* __restrict__ bias,
                                                 float* __restrict__ out, int N)
{
    int sub  = threadIdx.x & 15;
    int node = blockIdx.x * 16 + (threadIdx.x >> 4);
    if (node >= N) return;
    float ad = adst[node];
    float e = asrc[node] + ad;
    e = e >= 0.f ? e : NEG * e;
    float w = __expf(e);
    float acc = w * bf2f(xl2b[(size_t)node * OC + sub]);
    float den = w;
    int jb = rp[node], je = rp[node + 1];
    int j = jb;
    for (; j + 4 <= je; j += 4) {
        int s0 = ssrc[j], s1i = ssrc[j+1], s2i = ssrc[j+2], s3i = ssrc[j+3];
        float e0 = asrc[s0] + ad, e1 = asrc[s1i] + ad, e2 = asrc[s2i] + ad, e3 = asrc[s3i] + ad;
        float v0 = bf2f(xl2b[(size_t)s0 * OC + sub]);
        float v1 = bf2f(xl2b[(size_t)s1i * OC + sub]);
        float v2 = bf2f(xl2b[(size_t)s2i * OC + sub]);
        float v3 = bf2f(xl2b[(size_t)s3i * OC + sub]);
        e0 = e0 >= 0.f ? e0 : NEG * e0;  float w0 = __expf(e0);
        e1 = e1 >= 0.f ? e1 : NEG * e1;  float w1 = __expf(e1);
        e2 = e2 >= 0.f ? e2 : NEG * e2;  float w2 = __expf(e2);
        e3 = e3 >= 0.f ? e3 : NEG * e3;  float w3 = __expf(e3);
        den += w0 + w1 + w2 + w3;
        acc += w0 * v0 + w1 * v1 + w2 * v2 + w3 * v3;
    }
    for (; j < je; ++j) {
        int s = ssrc[j];
        float ev = asrc[s] + ad;
        ev = ev >= 0.f ? ev : NEG * ev;
        float wv = __expf(ev);
        acc += wv * bf2f(xl2b[(size_t)s * OC + sub]);
        den += wv;
    }
    float v = acc / (den + 1e-16f) + bias[sub];
    float m = v;
#pragma unroll
    for (int o = 1; o < 16; o <<= 1) m = fmaxf(m, __shfl_xor(m, o, 16));
    float ex = __expf(v - m);
    float ss = ex;
#pragma unroll
    for (int o = 1; o < 16; o <<= 1) ss += __shfl_xor(ss, o, 16);
    out[(size_t)node * OC + sub] = v - m - logf(ss);
}

extern "C" void kernel_launch(void* const* d_in, const int* in_sizes, int n_in,
                              void* d_out, int out_size, void* d_ws, size_t ws_size,
                              hipStream_t stream)
{
    const float* x   = (const float*)d_in[0];
    const int*   ei  = (const int*)d_in[1];
    const float* W1  = (const float*)d_in[2];
    const float* as1 = (const float*)d_in[3];
    const float* ad1 = (const float*)d_in[4];
    const float* b1  = (const float*)d_in[5];
    const float* W2  = (const float*)d_in[6];
    const float* as2 = (const float*)d_in[7];
    const float* ad2 = (const float*)d_in[8];
    const float* b2  = (const float*)d_in[9];
    float* out = (float*)d_out;

    const int N = in_sizes[0] / IN_C;   // 50000
    const int E = in_sizes[1] / 2;      // 800000
    const int NB = (N + 255) / 256;     // 196 scan blocks

    char* base = (char*)d_ws;
    unsigned short* xl1b = (unsigned short*)base;                      // N*256 bf16
    unsigned short* hb   = xl1b + (size_t)N * F1;                      // N*256 bf16
    unsigned short* w1t  = hb + (size_t)N * F1;                        // 256*256 bf16
    unsigned short* w2t  = w1t + 256 * 256;                            // 16*256 bf16
    unsigned short* xl2b = w2t + 16 * 256;                             // N*16 bf16
    float* asrc1 = (float*)(xl2b + (size_t)N * OC);                    // N*H1
    float* adst1 = asrc1 + (size_t)N * H1;                             // N*H1
    float* asrc2 = adst1 + (size_t)N * H1;                             // N
    float* adst2 = asrc2 + N;                                          // N
    int*   rp    = (int*)(adst2 + N);                                  // N+1
    int*   cnt   = rp + (N + 1);                                       // N
    int*   cur   = cnt + N;                                            // N
    int*   bsum  = cur + N;                                            // 1024
    int*   boff  = bsum + 1024;                                        // 1024
    int*   ssrc  = boff + 1024;                                        // E

    // ---- CSR build + weight conversion ----
    hipMemsetAsync(cnt, 0, (size_t)N * sizeof(int), stream);
    k_fuse0<<<(E + 255) / 256, 256, 0, stream>>>(ei, cnt, W1, W2, w1t, w2t, E);
    k_scan_a<<<NB, 256, 0, stream>>>(cnt, rp, bsum, N);
    k_scan_b<<<1, 256, 0, stream>>>(bsum, boff, NB);
    k_scan_c<<<NB, 256, 0, stream>>>(rp, boff, cnt, cur, N);
    k_scatter<<<(E + 255) / 256, 256, 0, stream>>>(ei, cur, ssrc, E);

    // ---- layer 1 ----
    k_gemm1<<<dim3((N + 127) / 128, 2), 256, 0, stream>>>(x, w1t, xl1b, N);
    k_att1<<<(N * H1 + 255) / 256, 256, 0, stream>>>(xl1b, as1, ad1, asrc1, adst1, N);
    k_gather1<<<(N + 3) / 4, 256, 0, stream>>>(rp, ssrc, xl1b, asrc1, adst1, b1, hb, N);

    // ---- layer 2 ----
    k_gemm2<<<(N + 63) / 64, 256, 0, stream>>>(hb, w2t, as2, ad2, xl2b, asrc2, adst2, N);
    k_gather2<<<(N + 15) / 16, 256, 0, stream>>>(rp, ssrc, xl2b, asrc2, adst2, b2, out, N);
}

// Round 8
// 322.445 us; speedup vs baseline: 1.1064x; 1.0344x over previous
//
#include <hip/hip_runtime.h>

#define IN_C 256
#define H1 8
#define C1 32
#define F1 256   // H1*C1
#define OC 16
#define NEG 0.2f

typedef short short8 __attribute__((ext_vector_type(8)));
typedef unsigned short ushort8 __attribute__((ext_vector_type(8)));
typedef float floatx4 __attribute__((ext_vector_type(4)));

__device__ __forceinline__ unsigned short f2bf(float f) {
    unsigned u = __builtin_bit_cast(unsigned, f);
    u = (u + 0x7fffu + ((u >> 16) & 1u)) >> 16;
    return (unsigned short)u;
}
__device__ __forceinline__ float bf2f(unsigned short h) {
    unsigned u = ((unsigned)h) << 16;
    return __builtin_bit_cast(float, u);
}

// ---------------- fused: hist (dst histogram) + W1/W2 bf16-transpose ----------------
__global__ __launch_bounds__(256) void k_fuse0(const int* __restrict__ ei,
                                               int* __restrict__ cnt,
                                               const float* __restrict__ W1,
                                               const float* __restrict__ W2,
                                               unsigned short* __restrict__ w1t,
                                               unsigned short* __restrict__ w2t, int E)
{
    int gid = blockIdx.x * 256 + threadIdx.x;
    if (gid < E) atomicAdd(&cnt[ei[E + gid]], 1);
    if (gid < 65536) {
        int n = gid >> 8, k = gid & 255;
        w1t[n * 256 + k] = f2bf(W1[k * 256 + n]);
    } else if (gid < 65536 + 4096) {
        int r = gid - 65536;
        int n = r >> 8, k = r & 255;        // n<16, k<256
        w2t[n * 256 + k] = f2bf(W2[k * 16 + n]);
    }
}

// ---------------- L1 GEMM (bf16 MFMA, fp32 A staged+converted) + fused att1 epilogue ----------------
// xl1b = x @ W1 (bf16 out); also asrc/adst [N,H1] via per-row dot with att vectors.
__global__ __launch_bounds__(256) void k_gemm1(const float* __restrict__ A,
                                               const unsigned short* __restrict__ Bt,
                                               const float* __restrict__ att_s,
                                               const float* __restrict__ att_d,
                                               unsigned short* __restrict__ Cb,
                                               float* __restrict__ asrc,
                                               float* __restrict__ adst, int M)
{
    __shared__ short As[128][40];   // +8 pad: conflict-free ds_read_b128
    __shared__ short Bs[128][40];
    const int tid  = threadIdx.x;
    const int lane = tid & 63;
    const int w    = tid >> 6;
    const int bm   = blockIdx.x * 128;
    const int bn   = blockIdx.y * 128;
    const int wm   = (w >> 1) * 64;
    const int wn   = (w & 1) * 64;
    const int srow = tid >> 1;          // staging row
    const int soff = (tid & 1) * 16;    // 16 elems
    floatx4 acc[4][4] = {};
    for (int k0 = 0; k0 < 256; k0 += 32) {
        __syncthreads();
        {   // stage A 128x32: fp32 load -> bf16 LDS
            int gr = bm + srow;
            float4 f0 = {0,0,0,0}, f1 = {0,0,0,0}, f2 = {0,0,0,0}, f3 = {0,0,0,0};
            if (gr < M) {
                const float4* p = (const float4*)(A + (size_t)gr * 256 + k0 + soff);
                f0 = p[0]; f1 = p[1]; f2 = p[2]; f3 = p[3];
            }
            ushort8 v0, v1;
            v0[0]=f2bf(f0.x); v0[1]=f2bf(f0.y); v0[2]=f2bf(f0.z); v0[3]=f2bf(f0.w);
            v0[4]=f2bf(f1.x); v0[5]=f2bf(f1.y); v0[6]=f2bf(f1.z); v0[7]=f2bf(f1.w);
            v1[0]=f2bf(f2.x); v1[1]=f2bf(f2.y); v1[2]=f2bf(f2.z); v1[3]=f2bf(f2.w);
            v1[4]=f2bf(f3.x); v1[5]=f2bf(f3.y); v1[6]=f2bf(f3.z); v1[7]=f2bf(f3.w);
            *(ushort8*)&As[srow][soff]     = v0;
            *(ushort8*)&As[srow][soff + 8] = v1;
        }
        {   // stage B 128x32 from w1t rows (already bf16)
            const ushort8* p = (const ushort8*)(Bt + (size_t)(bn + srow) * 256 + k0 + soff);
            *(ushort8*)&Bs[srow][soff]     = p[0];
            *(ushort8*)&Bs[srow][soff + 8] = p[1];
        }
        __syncthreads();
        short8 af[4], bf[4];
        const int q8 = (lane >> 4) * 8;
        const int l15i = lane & 15;
#pragma unroll
        for (int i = 0; i < 4; ++i) af[i] = *(const short8*)&As[wm + i * 16 + l15i][q8];
#pragma unroll
        for (int j = 0; j < 4; ++j) bf[j] = *(const short8*)&Bs[wn + j * 16 + l15i][q8];
#pragma unroll
        for (int i = 0; i < 4; ++i)
#pragma unroll
            for (int j = 0; j < 4; ++j)
                acc[i][j] = __builtin_amdgcn_mfma_f32_16x16x32_bf16(af[i], bf[j], acc[i][j], 0, 0, 0);
    }
    const int l15 = lane & 15;
    const int rq  = (lane >> 4) * 4;
    // heads covered by this wave: hA (tiles j=0,1), hB (tiles j=2,3)
    const int hA = (bn + wn) >> 5;
    const int hB = hA + 1;
    const float aS_A0 = att_s[hA * 32 + l15],      aS_A1 = att_s[hA * 32 + 16 + l15];
    const float aS_B0 = att_s[hB * 32 + l15],      aS_B1 = att_s[hB * 32 + 16 + l15];
    const float aD_A0 = att_d[hA * 32 + l15],      aD_A1 = att_d[hA * 32 + 16 + l15];
    const float aD_B0 = att_d[hB * 32 + l15],      aD_B1 = att_d[hB * 32 + 16 + l15];
#pragma unroll
    for (int i = 0; i < 4; ++i) {
#pragma unroll
        for (int reg = 0; reg < 4; ++reg) {
            int gr = bm + wm + i * 16 + rq + reg;
            float sA = acc[i][0][reg] * aS_A0 + acc[i][1][reg] * aS_A1;
            float dA = acc[i][0][reg] * aD_A0 + acc[i][1][reg] * aD_A1;
            float sB = acc[i][2][reg] * aS_B0 + acc[i][3][reg] * aS_B1;
            float dB = acc[i][2][reg] * aD_B0 + acc[i][3][reg] * aD_B1;
#pragma unroll
            for (int o = 1; o < 16; o <<= 1) {
                sA += __shfl_xor(sA, o, 16);  dA += __shfl_xor(dA, o, 16);
                sB += __shfl_xor(sB, o, 16);  dB += __shfl_xor(dB, o, 16);
            }
            if (gr < M) {
#pragma unroll
                for (int j = 0; j < 4; ++j)
                    Cb[(size_t)gr * 256 + bn + wn + j * 16 + l15] = f2bf(acc[i][j][reg]);
                if (l15 == 0) {
                    asrc[(size_t)gr * H1 + hA] = sA;  adst[(size_t)gr * H1 + hA] = dA;
                    asrc[(size_t)gr * H1 + hB] = sB;  adst[(size_t)gr * H1 + hB] = dB;
                }
            }
        }
    }
}

// ---------------- CSR scan ----------------
__global__ __launch_bounds__(256) void k_scan_a(const int* __restrict__ cnt,
                                                int* __restrict__ rp,
                                                int* __restrict__ bsum, int N)
{
    __shared__ int ws4[4];
    int t = threadIdx.x, lane = t & 63, wid = t >> 6;
    int i = blockIdx.x * 256 + t;
    int v = (i < N) ? cnt[i] : 0;
    int incl = v;
#pragma unroll
    for (int off = 1; off < 64; off <<= 1) {
        int tv = __shfl_up(incl, off, 64);
        if (lane >= off) incl += tv;
    }
    if (lane == 63) ws4[wid] = incl;
    __syncthreads();
    int add = 0;
    for (int w = 0; w < wid; ++w) add += ws4[w];
    incl += add;
    if (i < N) rp[i + 1] = incl;
    if (t == 255) bsum[blockIdx.x] = incl;
}

__global__ __launch_bounds__(256) void k_scan_b(const int* __restrict__ bsum,
                                                int* __restrict__ boff, int NB)
{
    __shared__ int ws4[4];
    int t = threadIdx.x, lane = t & 63, wid = t >> 6;
    int i0 = t * 4;
    int v[4];
#pragma unroll
    for (int k = 0; k < 4; ++k) { int i = i0 + k; v[k] = (i < NB) ? bsum[i] : 0; }
    int s = v[0] + v[1] + v[2] + v[3];
    int incl = s;
#pragma unroll
    for (int off = 1; off < 64; off <<= 1) {
        int tv = __shfl_up(incl, off, 64);
        if (lane >= off) incl += tv;
    }
    if (lane == 63) ws4[wid] = incl;
    __syncthreads();
    int wpre = 0;
    for (int w = 0; w < wid; ++w) wpre += ws4[w];
    int run = wpre + incl - s;
#pragma unroll
    for (int k = 0; k < 4; ++k) {
        int i = i0 + k;
        if (i < NB) boff[i] = run;
        run += v[k];
    }
}

__global__ __launch_bounds__(256) void k_scan_c(int* __restrict__ rp,
                                                const int* __restrict__ boff,
                                                const int* __restrict__ cnt,
                                                int* __restrict__ cur, int N)
{
    int i = blockIdx.x * 256 + threadIdx.x;
    if (i < N) {
        int v = rp[i + 1] + boff[blockIdx.x];
        rp[i + 1] = v;
        cur[i] = v - cnt[i];
    }
    if (i == 0) rp[0] = 0;
}

__global__ __launch_bounds__(256) void k_scatter(const int* __restrict__ ei,
                                                 int* __restrict__ cur,
                                                 int* __restrict__ ssrc, int E)
{
    int e = blockIdx.x * 256 + threadIdx.x;
    if (e >= E) return;
    int s = ei[e];
    int d = ei[E + e];
    int pos = atomicAdd(&cur[d], 1);
    ssrc[pos] = s;
}

// ---------------- L1 gather: 32 lanes x 8ch per edge row, 2 edges/wave-iter, 2x unroll ----------------
__global__ __launch_bounds__(256) void k_gather1(const int* __restrict__ rp,
                                                 const int* __restrict__ ssrc,
                                                 const unsigned short* __restrict__ xl,
                                                 const float* __restrict__ asrc,
                                                 const float* __restrict__ adst,
                                                 const float* __restrict__ bias,
                                                 unsigned short* __restrict__ hout, int N)
{
    int lane = threadIdx.x & 63;
    int node = blockIdx.x * 4 + (threadIdx.x >> 6);
    if (node >= N) return;
    int half = lane >> 5;           // which of 2 concurrent edges
    int l31  = lane & 31;
    int c8   = l31 * 8;             // channel base (8 channels, 16B)
    int h    = l31 >> 2;            // head of this channel group
    float ad = adst[(size_t)node * H1 + h];

    float4 a0 = {0,0,0,0}, a1 = {0,0,0,0};
    float den = 0.f;

    if (half == 0) {   // self-loop
        float e = asrc[(size_t)node * H1 + h] + ad;
        e = e >= 0.f ? e : NEG * e;
        float w = __expf(e);
        ushort8 r = *(const ushort8*)(xl + (size_t)node * F1 + c8);
        a0.x += w*bf2f(r[0]); a0.y += w*bf2f(r[1]); a0.z += w*bf2f(r[2]); a0.w += w*bf2f(r[3]);
        a1.x += w*bf2f(r[4]); a1.y += w*bf2f(r[5]); a1.z += w*bf2f(r[6]); a1.w += w*bf2f(r[7]);
        den += w;
    }

    int jb = rp[node];
    int Ecnt = rp[node + 1] - jb;
    int k = half;
    for (; k + 2 < Ecnt; k += 4) {
        int s0 = ssrc[jb + k];
        int s1 = ssrc[jb + k + 2];
        float e0 = asrc[(size_t)s0 * H1 + h] + ad;
        float e1 = asrc[(size_t)s1 * H1 + h] + ad;
        ushort8 r0 = *(const ushort8*)(xl + (size_t)s0 * F1 + c8);
        ushort8 r1 = *(const ushort8*)(xl + (size_t)s1 * F1 + c8);
        e0 = e0 >= 0.f ? e0 : NEG * e0;  float w0 = __expf(e0);
        e1 = e1 >= 0.f ? e1 : NEG * e1;  float w1 = __expf(e1);
        den += w0 + w1;
        a0.x += w0*bf2f(r0[0]) + w1*bf2f(r1[0]);
        a0.y += w0*bf2f(r0[1]) + w1*bf2f(r1[1]);
        a0.z += w0*bf2f(r0[2]) + w1*bf2f(r1[2]);
        a0.w += w0*bf2f(r0[3]) + w1*bf2f(r1[3]);
        a1.x += w0*bf2f(r0[4]) + w1*bf2f(r1[4]);
        a1.y += w0*bf2f(r0[5]) + w1*bf2f(r1[5]);
        a1.z += w0*bf2f(r0[6]) + w1*bf2f(r1[6]);
        a1.w += w0*bf2f(r0[7]) + w1*bf2f(r1[7]);
    }
    if (k < Ecnt) {
        int s = ssrc[jb + k];
        float e = asrc[(size_t)s * H1 + h] + ad;
        e = e >= 0.f ? e : NEG * e;
        float w = __expf(e);
        ushort8 r = *(const ushort8*)(xl + (size_t)s * F1 + c8);
        den += w;
        a0.x += w*bf2f(r[0]); a0.y += w*bf2f(r[1]); a0.z += w*bf2f(r[2]); a0.w += w*bf2f(r[3]);
        a1.x += w*bf2f(r[4]); a1.y += w*bf2f(r[5]); a1.z += w*bf2f(r[6]); a1.w += w*bf2f(r[7]);
    }
    // combine the two halves (channels identical across halves)
    a0.x += __shfl_xor(a0.x, 32);  a0.y += __shfl_xor(a0.y, 32);
    a0.z += __shfl_xor(a0.z, 32);  a0.w += __shfl_xor(a0.w, 32);
    a1.x += __shfl_xor(a1.x, 32);  a1.y += __shfl_xor(a1.y, 32);
    a1.z += __shfl_xor(a1.z, 32);  a1.w += __shfl_xor(a1.w, 32);
    den  += __shfl_xor(den, 32);
    if (half == 0) {
        float inv = 1.f / (den + 1e-16f);
        const float4* bv = (const float4*)(bias + c8);
        float4 b0 = bv[0], b1 = bv[1];
        ushort8 o;
        o[0] = f2bf(fmaxf(a0.x * inv + b0.x, 0.f));
        o[1] = f2bf(fmaxf(a0.y * inv + b0.y, 0.f));
        o[2] = f2bf(fmaxf(a0.z * inv + b0.z, 0.f));
        o[3] = f2bf(fmaxf(a0.w * inv + b0.w, 0.f));
        o[4] = f2bf(fmaxf(a1.x * inv + b1.x, 0.f));
        o[5] = f2bf(fmaxf(a1.y * inv + b1.y, 0.f));
        o[6] = f2bf(fmaxf(a1.z * inv + b1.z, 0.f));
        o[7] = f2bf(fmaxf(a1.w * inv + b1.w, 0.f));
        *(ushort8*)(hout + (size_t)node * F1 + c8) = o;
    }
}

// ---------------- L2 GEMM (bf16 MFMA, no LDS) + fused att2 epilogue ----------------
__global__ __launch_bounds__(256) void k_gemm2(const unsigned short* __restrict__ Hm,
                                               const unsigned short* __restrict__ W2t,
                                               const float* __restrict__ as2,
                                               const float* __restrict__ ad2,
                                               unsigned short* __restrict__ xl2b,
                                               float* __restrict__ asrc,
                                               float* __restrict__ adst, int N)
{
    const int lane = threadIdx.x & 63;
    const int wid  = threadIdx.x >> 6;
    const int rowbase = blockIdx.x * 64 + wid * 16;
    const int col = lane & 15;
    const int q8  = (lane >> 4) * 8;
    const int m   = rowbase + col;            // A-frag row
    const bool mv = m < N;
    const unsigned short* arow = Hm + (size_t)m * 256 + q8;
    const unsigned short* brow = W2t + (size_t)col * 256 + q8;
    floatx4 acc = {0.f, 0.f, 0.f, 0.f};
#pragma unroll
    for (int t = 0; t < 8; ++t) {
        short8 af = {0,0,0,0,0,0,0,0};
        if (mv) af = *(const short8*)(arow + t * 32);
        short8 bf = *(const short8*)(brow + t * 32);
        acc = __builtin_amdgcn_mfma_f32_16x16x32_bf16(af, bf, acc, 0, 0, 0);
    }
    float s_as = as2[col], s_ad = ad2[col];
    const int rq = (lane >> 4) * 4;
#pragma unroll
    for (int reg = 0; reg < 4; ++reg) {
        int row = rowbase + rq + reg;
        float v = acc[reg];
        float s1 = v * s_as, s2 = v * s_ad;
#pragma unroll
        for (int o = 1; o < 16; o <<= 1) { s1 += __shfl_xor(s1, o, 16); s2 += __shfl_xor(s2, o, 16); }
        if (row < N) {
            xl2b[(size_t)row * OC + col] = f2bf(v);
            if (col == 0) { asrc[row] = s1; adst[row] = s2; }
        }
    }
}

// ---------------- L2 gather (bf16 rows, 4x unrolled) + log_softmax ----------------
__global__ __launch_bounds__(256) void k_gather2(const int* __restrict__ rp,
                                                 const int* __restrict__ ssrc,
                                                 const unsigned short* __restrict__ xl2b,
                                                 const float* __restrict__ asrc,
                                                 const float* __restrict__ adst,
                                                 const float* __restrict__ bias,
                                                 float* __restrict__ out, int N)
{
    int sub  = threadIdx.x & 15;
    int node = blockIdx.x * 16 + (threadIdx.x >> 4);
    if (node >= N) return;
    float ad = adst[node];
    float e = asrc[node] + ad;
    e = e >= 0.f ? e : NEG * e;
    float w = __expf(e);
    float acc = w * bf2f(xl2b[(size_t)node * OC + sub]);
    float den = w;
    int jb = rp[node], je = rp[node + 1];
    int j = jb;
    for (; j + 4 <= je; j += 4) {
        int s0 = ssrc[j], s1i = ssrc[j+1], s2i = ssrc[j+2], s3i = ssrc[j+3];
        float e0 = asrc[s0] + ad, e1 = asrc[s1i] + ad, e2 = asrc[s2i] + ad, e3 = asrc[s3i] + ad;
        float v0 = bf2f(xl2b[(size_t)s0 * OC + sub]);
        float v1 = bf2f(xl2b[(size_t)s1i * OC + sub]);
        float v2 = bf2f(xl2b[(size_t)s2i * OC + sub]);
        float v3 = bf2f(xl2b[(size_t)s3i * OC + sub]);
        e0 = e0 >= 0.f ? e0 : NEG * e0;  float w0 = __expf(e0);
        e1 = e1 >= 0.f ? e1 : NEG * e1;  float w1 = __expf(e1);
        e2 = e2 >= 0.f ? e2 : NEG * e2;  float w2 = __expf(e2);
        e3 = e3 >= 0.f ? e3 : NEG * e3;  float w3 = __expf(e3);
        den += w0 + w1 + w2 + w3;
        acc += w0 * v0 + w1 * v1 + w2 * v2 + w3 * v3;
    }
    for (; j < je; ++j) {
        int s = ssrc[j];
        float ev = asrc[s] + ad;
        ev = ev >= 0.f ? ev : NEG * ev;
        float wv = __expf(ev);
        acc += wv * bf2f(xl2b[(size_t)s * OC + sub]);
        den += wv;
    }
    float v = acc / (den + 1e-16f) + bias[sub];
    float m = v;
#pragma unroll
    for (int o = 1; o < 16; o <<= 1) m = fmaxf(m, __shfl_xor(m, o, 16));
    float ex = __expf(v - m);
    float ss = ex;
#pragma unroll
    for (int o = 1; o < 16; o <<= 1) ss += __shfl_xor(ss, o, 16);
    out[(size_t)node * OC + sub] = v - m - logf(ss);
}

extern "C" void kernel_launch(void* const* d_in, const int* in_sizes, int n_in,
                              void* d_out, int out_size, void* d_ws, size_t ws_size,
                              hipStream_t stream)
{
    const float* x   = (const float*)d_in[0];
    const int*   ei  = (const int*)d_in[1];
    const float* W1  = (const float*)d_in[2];
    const float* as1 = (const float*)d_in[3];
    const float* ad1 = (const float*)d_in[4];
    const float* b1  = (const float*)d_in[5];
    const float* W2  = (const float*)d_in[6];
    const float* as2 = (const float*)d_in[7];
    const float* ad2 = (const float*)d_in[8];
    const float* b2  = (const float*)d_in[9];
    float* out = (float*)d_out;

    const int N = in_sizes[0] / IN_C;   // 50000
    const int E = in_sizes[1] / 2;      // 800000
    const int NB = (N + 255) / 256;     // 196 scan blocks

    char* base = (char*)d_ws;
    unsigned short* xl1b = (unsigned short*)base;                      // N*256 bf16
    unsigned short* hb   = xl1b + (size_t)N * F1;                      // N*256 bf16
    unsigned short* w1t  = hb + (size_t)N * F1;                        // 256*256 bf16
    unsigned short* w2t  = w1t + 256 * 256;                            // 16*256 bf16
    unsigned short* xl2b = w2t + 16 * 256;                             // N*16 bf16
    float* asrc1 = (float*)(xl2b + (size_t)N * OC);                    // N*H1
    float* adst1 = asrc1 + (size_t)N * H1;                             // N*H1
    float* asrc2 = adst1 + (size_t)N * H1;                             // N
    float* adst2 = asrc2 + N;                                          // N
    int*   rp    = (int*)(adst2 + N);                                  // N+1
    int*   cnt   = rp + (N + 1);                                       // N
    int*   cur   = cnt + N;                                            // N
    int*   bsum  = cur + N;                                            // 1024
    int*   boff  = bsum + 1024;                                        // 1024
    int*   ssrc  = boff + 1024;                                        // E

    // ---- CSR build + weight conversion ----
    hipMemsetAsync(cnt, 0, (size_t)N * sizeof(int), stream);
    k_fuse0<<<(E + 255) / 256, 256, 0, stream>>>(ei, cnt, W1, W2, w1t, w2t, E);
    k_scan_a<<<NB, 256, 0, stream>>>(cnt, rp, bsum, N);
    k_scan_b<<<1, 256, 0, stream>>>(bsum, boff, NB);
    k_scan_c<<<NB, 256, 0, stream>>>(rp, boff, cnt, cur, N);
    k_scatter<<<(E + 255) / 256, 256, 0, stream>>>(ei, cur, ssrc, E);

    // ---- layer 1 (att1 fused into gemm1 epilogue) ----
    k_gemm1<<<dim3((N + 127) / 128, 2), 256, 0, stream>>>(x, w1t, as1, ad1, xl1b, asrc1, adst1, N);
    k_gather1<<<(N + 3) / 4, 256, 0, stream>>>(rp, ssrc, xl1b, asrc1, adst1, b1, hb, N);

    // ---- layer 2 ----
    k_gemm2<<<(N + 63) / 64, 256, 0, stream>>>(hb, w2t, as2, ad2, xl2b, asrc2, adst2, N);
    k_gather2<<<(N + 15) / 16, 256, 0, stream>>>(rp, ssrc, xl2b, asrc2, adst2, b2, out, N);
}